// Round 6
// baseline (720.327 us; speedup 1.0000x reference)
//
#include <hip/hip_runtime.h>

#define S_DIM 256
#define I_DIM 64
#define O_DIM 64
#define BATCH 64
#define TT 2048
#define CHUNK 32
#define NCHUNK (TT / CHUNK)     // 64
#define NTASK (BATCH * NCHUNK)  // 4096

typedef __attribute__((ext_vector_type(8))) short short8v;      // 8 bf16
typedef _Float16 half8v __attribute__((ext_vector_type(8)));    // 8 fp16
typedef __attribute__((ext_vector_type(4))) float float4v;      // MFMA acc

__device__ inline unsigned short f2bf(float f) {
  unsigned x = __float_as_uint(f);
  unsigned r = (x + 0x7FFFu + ((x >> 16) & 1u)) >> 16;  // RNE
  return (unsigned short)r;
}

// ------------- power-stack doubling: stack[m+j] = stack[j] @ stack[m-1] -------------
__global__ void k_powstage(float* __restrict__ stack, int m) {
  const int j = blockIdx.x >> 8;
  const int i = blockIdx.x & 255;
  const int d = threadIdx.x;
  const float* A = stack + (size_t)j * 65536 + i * 256;
  const float* Bm = stack + (size_t)(m - 1) * 65536;
  float acc = 0.f;
#pragma unroll 8
  for (int k = 0; k < 256; ++k) acc += A[k] * Bm[k * 256 + d];
  stack[(size_t)(m + j) * 65536 + i * 256 + d] = acc;
}

// ------------- f32 -> bf16 elementwise -------------
__global__ void k_bfcvt(const float* __restrict__ src, unsigned short* __restrict__ dst) {
  int i = blockIdx.x * 256 + threadIdx.x;
  float4 v = reinterpret_cast<const float4*>(src)[i];
  ushort4 o;
  o.x = f2bf(v.x); o.y = f2bf(v.y); o.z = f2bf(v.z); o.w = f2bf(v.w);
  reinterpret_cast<ushort4*>(dst)[i] = o;
}

// ------------- f32 matrix -> fp16 hi/lo split -------------
__global__ void k_fsplit16(const float* __restrict__ src, _Float16* __restrict__ hi,
                           _Float16* __restrict__ lo) {
  int idx = blockIdx.x * 256 + threadIdx.x;
  float a = src[idx];
  _Float16 h = (_Float16)a;
  hi[idx] = h;
  lo[idx] = (_Float16)(a - (float)h);
}

// ------------- weight split: Wd[n][k] = concat(s1,s2) rows; hi/lo bf16 -------------
__global__ void k_wsplit(const float* __restrict__ s1, const float* __restrict__ s2,
                         int K1, int K2, unsigned short* __restrict__ hi,
                         unsigned short* __restrict__ lo, int total) {
  int idx = blockIdx.x * 256 + threadIdx.x;
  if (idx >= total) return;
  int KT = K1 + K2;
  int n = idx / KT, k = idx - n * KT;
  float a = (k < K1) ? s1[n * K1 + k] : s2[n * K2 + (k - K1)];
  unsigned short h = f2bf(a);
  hi[idx] = h;
  lo[idx] = f2bf(a - __uint_as_float((unsigned)h << 16));
}

// ---------------- register-direct split-bf16 MFMA GEMM: out = [A1|A2] @ W^T ----------------
// No LDS, no barriers. Wave = 32 rows x (N_TOT/WIN) cols. A loaded global->reg
// (each element read exactly once), W served from L2 (~655 MB total -> ~19 us).
// A prefetched one kk-step ahead in registers.
template <int N_TOT, int K1, int K2, int WIM, int WIN>
__global__ __launch_bounds__(WIM * WIN * 64) void k_rgemm(
    const float* __restrict__ A1, const float* __restrict__ A2,
    const unsigned short* __restrict__ Whi, const unsigned short* __restrict__ Wlo,
    float* __restrict__ out) {
  constexpr int KT = K1 + K2;        // 320
  constexpr int NKK = KT / 32;       // 10 k-steps
  constexpr int NF = N_TOT / WIN / 16;
  constexpr int MT = WIM * 32;

  const int tid = threadIdx.x;
  const int w = tid >> 6, l = tid & 63;
  const int lo16 = l & 15, hi4 = l >> 4;
  const int wm = w % WIM, wn = w / WIM;
  const size_t R0 = (size_t)blockIdx.x * MT + wm * 32;
  const int C0 = wn * (N_TOT / WIN);

  float4v acc[2][NF];
#pragma unroll
  for (int m = 0; m < 2; ++m)
#pragma unroll
    for (int n = 0; n < NF; ++n) acc[m][n] = (float4v){0.f, 0.f, 0.f, 0.f};

  // A fragment source for k-step kk, M-frag m (compile-time branch under unroll)
  auto aptr = [&](int kk, int m) -> const float* {
    const int k0 = kk * 32;
    if (k0 < K1) return A1 + (R0 + m * 16 + lo16) * K1 + k0 + hi4 * 8;
    return A2 + (R0 + m * 16 + lo16) * K2 + (k0 - K1) + hi4 * 8;
  };

  float4 fc[2][2], fn[2][2];
#pragma unroll
  for (int m = 0; m < 2; ++m)
#pragma unroll
    for (int h = 0; h < 2; ++h)
      fc[m][h] = *reinterpret_cast<const float4*>(aptr(0, m) + h * 4);

#pragma unroll
  for (int kk = 0; kk < NKK; ++kk) {
    if (kk + 1 < NKK) {
#pragma unroll
      for (int m = 0; m < 2; ++m)
#pragma unroll
        for (int h = 0; h < 2; ++h)
          fn[m][h] = *reinterpret_cast<const float4*>(aptr(kk + 1, m) + h * 4);
    }
    // in-register f32 -> hi/lo bf16 split
    short8v ah[2], al[2];
#pragma unroll
    for (int m = 0; m < 2; ++m) {
#pragma unroll
      for (int j = 0; j < 4; ++j) {
        float x0 = (&fc[m][0].x)[j], x1 = (&fc[m][1].x)[j];
        unsigned short h0 = f2bf(x0), h1 = f2bf(x1);
        ah[m][j] = (short)h0;
        ah[m][j + 4] = (short)h1;
        al[m][j]     = (short)f2bf(x0 - __uint_as_float((unsigned)h0 << 16));
        al[m][j + 4] = (short)f2bf(x1 - __uint_as_float((unsigned)h1 << 16));
      }
    }
#pragma unroll
    for (int nf = 0; nf < NF; ++nf) {
      const size_t wo = (size_t)(C0 + nf * 16 + lo16) * KT + kk * 32 + hi4 * 8;
      short8v wh = *reinterpret_cast<const short8v*>(Whi + wo);
      short8v wl = *reinterpret_cast<const short8v*>(Wlo + wo);
#pragma unroll
      for (int m = 0; m < 2; ++m) {
        acc[m][nf] = __builtin_amdgcn_mfma_f32_16x16x32_bf16(ah[m], wh, acc[m][nf], 0, 0, 0);
        acc[m][nf] = __builtin_amdgcn_mfma_f32_16x16x32_bf16(ah[m], wl, acc[m][nf], 0, 0, 0);
        acc[m][nf] = __builtin_amdgcn_mfma_f32_16x16x32_bf16(al[m], wh, acc[m][nf], 0, 0, 0);
      }
    }
#pragma unroll
    for (int m = 0; m < 2; ++m)
#pragma unroll
      for (int h = 0; h < 2; ++h) fc[m][h] = fn[m][h];
  }

  // epilogue: C/D layout col=lane&15, row=(lane>>4)*4+reg
#pragma unroll
  for (int m = 0; m < 2; ++m)
#pragma unroll
    for (int nf = 0; nf < NF; ++nf) {
      const size_t r_base = R0 + m * 16 + hi4 * 4;
      const int col = C0 + nf * 16 + lo16;
#pragma unroll
      for (int rr = 0; rr < 4; ++rr)
        out[(r_base + rr) * N_TOT + col] = acc[m][nf][rr];
    }
}

// ---------------- MFMA chunk scan: 16 tasks/block, 32 steps, fp16-2split F ----------------
__global__ __launch_bounds__(1024, 4) void k_mscan(const _Float16* __restrict__ Fhi,
                                                   const _Float16* __restrict__ Flo,
                                                   float* __restrict__ U,
                                                   float* __restrict__ Lst) {
  __shared__ _Float16 sh[16 * 264];
  __shared__ _Float16 sl[16 * 264];

  const int tid = threadIdx.x;
  const int wv = tid >> 6;
  const int l = tid & 63;
  const int lo16 = l & 15, hi4 = l >> 4;
  const int dcol = wv * 16 + lo16;

  const int c = blockIdx.x >> 2;
  const int b0 = (blockIdx.x & 3) * 16;

  half8v fh[8], fl[8];
#pragma unroll
  for (int kk = 0; kk < 8; ++kk) {
    const size_t fo = (size_t)dcol * 256 + kk * 32 + hi4 * 8;
    fh[kk] = *reinterpret_cast<const half8v*>(Fhi + fo);
    fl[kk] = *reinterpret_cast<const half8v*>(Flo + fo);
  }

  const size_t ustr = (size_t)TT * 256;
  float* ub = U + ((size_t)b0 * TT + c * CHUNK) * 256 + dcol;

  float u_cur[4], u_nxt[4];
#pragma unroll
  for (int r = 0; r < 4; ++r) u_cur[r] = ub[(size_t)(hi4 * 4 + r) * ustr];

  for (int k = 0; k < CHUNK; ++k) {
    if (k < CHUNK - 1) {
#pragma unroll
      for (int r = 0; r < 4; ++r)
        u_nxt[r] = ub[(size_t)(hi4 * 4 + r) * ustr + (k + 1) * 256];
    }
    float4v acc;
#pragma unroll
    for (int r = 0; r < 4; ++r) acc[r] = u_cur[r];

    if (k) {
#pragma unroll
      for (int kk = 0; kk < 8; ++kk) {
        const int ao = lo16 * 264 + kk * 32 + hi4 * 8;
        half8v ah = *reinterpret_cast<const half8v*>(&sh[ao]);
        half8v al = *reinterpret_cast<const half8v*>(&sl[ao]);
        acc = __builtin_amdgcn_mfma_f32_16x16x32_f16(ah, fh[kk], acc, 0, 0, 0);
        acc = __builtin_amdgcn_mfma_f32_16x16x32_f16(ah, fl[kk], acc, 0, 0, 0);
        acc = __builtin_amdgcn_mfma_f32_16x16x32_f16(al, fh[kk], acc, 0, 0, 0);
      }
    }

    _Float16 xh[4], xl[4];
#pragma unroll
    for (int r = 0; r < 4; ++r) {
      float x = acc[r];
      ub[(size_t)(hi4 * 4 + r) * ustr + k * 256] = x;
      if (k == CHUNK - 1) Lst[((size_t)c * BATCH + b0 + hi4 * 4 + r) * 256 + dcol] = x;
      _Float16 h = (_Float16)x;
      xh[r] = h;
      xl[r] = (_Float16)(x - (float)h);
    }
    __syncthreads();
#pragma unroll
    for (int r = 0; r < 4; ++r) {
      const int m = hi4 * 4 + r;
      sh[m * 264 + dcol] = xh[r];
      sl[m * 264 + dcol] = xl[r];
    }
    __syncthreads();
#pragma unroll
    for (int r = 0; r < 4; ++r) u_cur[r] = u_nxt[r];
  }
}

// ---------------- MFMA chunk carry: e_{c+1} = F^32 e_c + Lst[c] -> Ebf (bf16) ----------------
__global__ __launch_bounds__(1024, 4) void k_mcarry(const _Float16* __restrict__ FLhi,
                                                    const _Float16* __restrict__ FLlo,
                                                    const float* __restrict__ state0,
                                                    const float* __restrict__ Lst,
                                                    unsigned short* __restrict__ Ebf) {
  __shared__ _Float16 sh[16 * 264];
  __shared__ _Float16 sl[16 * 264];

  const int tid = threadIdx.x;
  const int wv = tid >> 6;
  const int l = tid & 63;
  const int lo16 = l & 15, hi4 = l >> 4;
  const int dcol = wv * 16 + lo16;
  const int b0 = blockIdx.x * 16;

  half8v fh[8], fl[8];
#pragma unroll
  for (int kk = 0; kk < 8; ++kk) {
    const size_t fo = (size_t)dcol * 256 + kk * 32 + hi4 * 8;
    fh[kk] = *reinterpret_cast<const half8v*>(FLhi + fo);
    fl[kk] = *reinterpret_cast<const half8v*>(FLlo + fo);
  }

#pragma unroll
  for (int r = 0; r < 4; ++r) {
    const int m = hi4 * 4 + r;
    float x = state0[(size_t)(b0 + m) * 256 + dcol];
    Ebf[(size_t)(b0 + m) * 256 + dcol] = f2bf(x);
    _Float16 h = (_Float16)x;
    sh[m * 264 + dcol] = h;
    sl[m * 264 + dcol] = (_Float16)(x - (float)h);
  }
  __syncthreads();

  for (int cstep = 0; cstep < NCHUNK - 1; ++cstep) {
    float4v acc;
#pragma unroll
    for (int r = 0; r < 4; ++r)
      acc[r] = Lst[((size_t)cstep * BATCH + b0 + hi4 * 4 + r) * 256 + dcol];
#pragma unroll
    for (int kk = 0; kk < 8; ++kk) {
      const int ao = lo16 * 264 + kk * 32 + hi4 * 8;
      half8v ah = *reinterpret_cast<const half8v*>(&sh[ao]);
      half8v al = *reinterpret_cast<const half8v*>(&sl[ao]);
      acc = __builtin_amdgcn_mfma_f32_16x16x32_f16(ah, fh[kk], acc, 0, 0, 0);
      acc = __builtin_amdgcn_mfma_f32_16x16x32_f16(ah, fl[kk], acc, 0, 0, 0);
      acc = __builtin_amdgcn_mfma_f32_16x16x32_f16(al, fh[kk], acc, 0, 0, 0);
    }
    _Float16 xh[4], xl[4];
#pragma unroll
    for (int r = 0; r < 4; ++r) {
      float x = acc[r];
      Ebf[((size_t)(cstep + 1) * BATCH + b0 + hi4 * 4 + r) * 256 + dcol] = f2bf(x);
      _Float16 h = (_Float16)x;
      xh[r] = h;
      xl[r] = (_Float16)(x - (float)h);
    }
    __syncthreads();
#pragma unroll
    for (int r = 0; r < 4; ++r) {
      const int m = hi4 * 4 + r;
      sh[m * 264 + dcol] = xh[r];
      sl[m * 264 + dcol] = xl[r];
    }
    __syncthreads();
  }
}

// ---------------- correction: states[task, j, :] += F^{j+1} @ e[task]  (bf16 MFMA) ----------------
__global__ __launch_bounds__(256) void k_corr(const unsigned short* __restrict__ Ebf,
                                              const unsigned short* __restrict__ stackbf,
                                              float* __restrict__ states) {
  const int tb = blockIdx.x & 127;
  const int jb = blockIdx.x >> 7;
  const int tid = threadIdx.x;
  const int w = tid >> 6;
  const int l = tid & 63;
  const int lo = l & 15, hi = l >> 4;

  const int M0 = tb * 32 + (w & 1) * 16;
  const int nbase = (w >> 1) * 128;
  const unsigned short* Bj = stackbf + (size_t)jb * 65536;

  float4v acc[8];
#pragma unroll
  for (int nf = 0; nf < 8; ++nf) acc[nf] = (float4v){0.f, 0.f, 0.f, 0.f};

#pragma unroll
  for (int kk = 0; kk < 8; ++kk) {
    const int k0 = kk * 32;
    short8v a = *reinterpret_cast<const short8v*>(Ebf + (size_t)(M0 + lo) * 256 + k0 + hi * 8);
#pragma unroll
    for (int nf = 0; nf < 8; ++nf) {
      const int d0 = nbase + nf * 16;
      short8v bv = *reinterpret_cast<const short8v*>(Bj + (size_t)(d0 + lo) * 256 + k0 + hi * 8);
      acc[nf] = __builtin_amdgcn_mfma_f32_16x16x32_bf16(a, bv, acc[nf], 0, 0, 0);
    }
  }

#pragma unroll
  for (int nf = 0; nf < 8; ++nf) {
    const int d = nbase + nf * 16 + lo;
#pragma unroll
    for (int r = 0; r < 4; ++r) {
      const int task = M0 + hi * 4 + r;
      const int bb = task & 63, cc = task >> 6;
      size_t addr = (((size_t)bb * TT) + cc * CHUNK + jb) * 256 + d;
      states[addr] = states[addr] + acc[nf][r];
    }
  }
}

extern "C" void kernel_launch(void* const* d_in, const int* in_sizes, int n_in,
                              void* d_out, int out_size, void* d_ws, size_t ws_size,
                              hipStream_t stream) {
  const float* state  = (const float*)d_in[0];
  const float* inputs = (const float*)d_in[1];
  const float* eps_W  = (const float*)d_in[2];
  const float* eps_V  = (const float*)d_in[3];
  const float* F      = (const float*)d_in[4];
  const float* B_mat  = (const float*)d_in[5];
  const float* H      = (const float*)d_in[6];
  const float* SW     = (const float*)d_in[7];
  const float* SV     = (const float*)d_in[8];

  float* out = (float*)d_out;
  float* states_out = out;                                 // [64][2048][256]
  float* obs_out = out + (size_t)BATCH * TT * S_DIM;       // [64][2048][64]

  // ws (~912 KB): bf16 weight splits + fp16 F splits
  unsigned short* ws16 = (unsigned short*)d_ws;
  unsigned short* whi1 = ws16;                 // [256][320]
  unsigned short* wlo1 = whi1 + 81920;
  unsigned short* whi2 = wlo1 + 81920;         // [64][320]
  unsigned short* wlo2 = whi2 + 20480;
  _Float16* Fhi  = (_Float16*)(wlo2 + 20480);  // [256][256]
  _Float16* Flo  = Fhi + 65536;
  _Float16* FLhi = Flo + 65536;                // (F^32) [256][256]
  _Float16* FLlo = FLhi + 65536;

  // big scratch in the dead obs region (18 MB of 33.5 MB)
  float* Lst              = obs_out;                                   // [64][64][256] f32
  float* stack_F          = Lst + (size_t)NCHUNK * BATCH * 256;        // [32][256][256] f32
  unsigned short* stackbf = (unsigned short*)(stack_F + (size_t)32 * 65536);
  unsigned short* Ebf     = stackbf + (size_t)32 * 65536;              // [64][64][256] bf16

  // power stack F^1..F^32 by doubling
  hipMemcpyAsync(stack_F, F, 65536 * sizeof(float), hipMemcpyDeviceToDevice, stream);
  k_powstage<<<1 * 256, 256, 0, stream>>>(stack_F, 1);
  k_powstage<<<2 * 256, 256, 0, stream>>>(stack_F, 2);
  k_powstage<<<4 * 256, 256, 0, stream>>>(stack_F, 4);
  k_powstage<<<8 * 256, 256, 0, stream>>>(stack_F, 8);
  k_powstage<<<16 * 256, 256, 0, stream>>>(stack_F, 16);
  k_bfcvt<<<32 * 65536 / 4 / 256, 256, 0, stream>>>(stack_F, stackbf);

  // fp16 splits for the scan/carry matrices
  k_fsplit16<<<256, 256, 0, stream>>>(F, Fhi, Flo);
  k_fsplit16<<<256, 256, 0, stream>>>(stack_F + (size_t)31 * 65536, FLhi, FLlo);

  // bf16 weight splits (K-major concat rows)
  k_wsplit<<<320, 256, 0, stream>>>(B_mat, SW, 64, 256, whi1, wlo1, 256 * 320);
  k_wsplit<<<80, 256, 0, stream>>>(H, SV, 256, 64, whi2, wlo2, 64 * 320);

  // U = inputs@B^T + eps_W@SW^T  (register-direct split-bf16 MFMA)
  k_rgemm<256, 64, 256, 2, 2><<<BATCH * TT / 64, 256, 0, stream>>>(
      inputs, eps_W, whi1, wlo1, states_out);

  // pass 1: MFMA local scans (zero init), y in place + Lst
  k_mscan<<<NTASK / 16, 1024, 0, stream>>>(Fhi, Flo, states_out, Lst);

  // carry across chunks -> Ebf
  k_mcarry<<<BATCH / 16, 1024, 0, stream>>>(FLhi, FLlo, state, Lst, Ebf);

  // correction: states = y + F^{j+1} e
  k_corr<<<32 * 128, 256, 0, stream>>>(Ebf, stackbf, states_out);

  // observations = states@H^T + eps_V@SV^T (register-direct split-bf16 MFMA)
  k_rgemm<64, 256, 64, 4, 1><<<BATCH * TT / 128, 256, 0, stream>>>(
      states_out, eps_V, whi2, wlo2, obs_out);
}

// Round 7
// 632.438 us; speedup vs baseline: 1.1390x; 1.1390x over previous
//
#include <hip/hip_runtime.h>
#include <hip/hip_bf16.h>

#define S_DIM 256
#define I_DIM 64
#define O_DIM 64
#define BATCH 64
#define TT 2048
#define CHUNK 32
#define NCHUNK (TT / CHUNK)     // 64
#define NTASK (BATCH * NCHUNK)  // 4096

typedef __attribute__((ext_vector_type(8))) short short8v;      // 8 bf16
typedef _Float16 half8v __attribute__((ext_vector_type(8)));    // 8 fp16
typedef __attribute__((ext_vector_type(4))) float float4v;      // MFMA acc

__device__ inline unsigned short f2bf(float f) {
  unsigned x = __float_as_uint(f);
  unsigned r = (x + 0x7FFFu + ((x >> 16) & 1u)) >> 16;  // RNE
  return (unsigned short)r;
}

// RNE f32->bf16 via HIP intrinsic (compiler emits packed v_cvt where possible)
__device__ inline short bfr(float x) {
  __hip_bfloat16 h = __float2bfloat16(x);
  return __builtin_bit_cast(short, h);
}

// ------------- power-stack doubling: stack[m+j] = stack[j] @ stack[m-1] -------------
__global__ void k_powstage(float* __restrict__ stack, int m) {
  const int j = blockIdx.x >> 8;
  const int i = blockIdx.x & 255;
  const int d = threadIdx.x;
  const float* A = stack + (size_t)j * 65536 + i * 256;
  const float* Bm = stack + (size_t)(m - 1) * 65536;
  float acc = 0.f;
#pragma unroll 8
  for (int k = 0; k < 256; ++k) acc += A[k] * Bm[k * 256 + d];
  stack[(size_t)(m + j) * 65536 + i * 256 + d] = acc;
}

// ------------- f32 -> bf16 elementwise -------------
__global__ void k_bfcvt(const float* __restrict__ src, unsigned short* __restrict__ dst) {
  int i = blockIdx.x * 256 + threadIdx.x;
  float4 v = reinterpret_cast<const float4*>(src)[i];
  ushort4 o;
  o.x = f2bf(v.x); o.y = f2bf(v.y); o.z = f2bf(v.z); o.w = f2bf(v.w);
  reinterpret_cast<ushort4*>(dst)[i] = o;
}

// ------------- f32 matrix -> fp16 hi/lo split -------------
__global__ void k_fsplit16(const float* __restrict__ src, _Float16* __restrict__ hi,
                           _Float16* __restrict__ lo) {
  int idx = blockIdx.x * 256 + threadIdx.x;
  float a = src[idx];
  _Float16 h = (_Float16)a;
  hi[idx] = h;
  lo[idx] = (_Float16)(a - (float)h);
}

// ------------- weight convert: Wd[n][k] = concat(s1,s2) rows, single bf16 -------------
__global__ void k_wcvt(const float* __restrict__ s1, const float* __restrict__ s2,
                       int K1, int K2, unsigned short* __restrict__ hi, int total) {
  int idx = blockIdx.x * 256 + threadIdx.x;
  if (idx >= total) return;
  int KT = K1 + K2;
  int n = idx / KT, k = idx - n * KT;
  float a = (k < K1) ? s1[n * K1 + k] : s2[n * K2 + (k - K1)];
  hi[idx] = f2bf(a);
}

// ---------------- streaming bf16 MFMA GEMM: out = [A1|A2] @ W^T ----------------
// No LDS, no barriers. Wave tile 32 rows x 64 cols (acc=32 VGPR). Block spans all
// N columns so each A row is read exactly once. A prefetched 2 kk-steps ahead
// (HBM ~900cy), W 1 ahead (L2 ~250cy). All rotation indices compile-time.
template <int N_TOT, int K1, int K2, int WIM, int WIN>
__global__ __launch_bounds__(WIM * WIN * 64) void k_rgemm(
    const float* __restrict__ A1, const float* __restrict__ A2,
    const unsigned short* __restrict__ W, float* __restrict__ out) {
  constexpr int KT = K1 + K2;           // 320
  constexpr int NKK = KT / 32;          // 10 k-steps
  constexpr int NF = N_TOT / WIN / 16;  // 4 col-frags per wave
  constexpr int MT = WIM * 32;          // rows per block

  const int tid = threadIdx.x;
  const int w = tid >> 6, l = tid & 63;
  const int lo16 = l & 15, hi4 = l >> 4;
  const int wm = w % WIM, wn = w / WIM;
  const size_t R0 = (size_t)blockIdx.x * MT + wm * 32;
  const int C0 = wn * (N_TOT / WIN);

  float4v acc[2][NF];
#pragma unroll
  for (int m = 0; m < 2; ++m)
#pragma unroll
    for (int n = 0; n < NF; ++n) acc[m][n] = (float4v){0.f, 0.f, 0.f, 0.f};

  auto aload = [&](int kk, int m, int h) -> float4 {
    const int k0 = kk * 32;
    const float* p = (k0 < K1)
                         ? A1 + (R0 + m * 16 + lo16) * K1 + k0 + hi4 * 8
                         : A2 + (R0 + m * 16 + lo16) * K2 + (k0 - K1) + hi4 * 8;
    return *reinterpret_cast<const float4*>(p + h * 4);
  };
  auto wload = [&](int kk, int nf) -> short8v {
    return *reinterpret_cast<const short8v*>(
        W + (size_t)(C0 + nf * 16 + lo16) * KT + kk * 32 + hi4 * 8);
  };

  float4 a[3][2][2];    // [slot][m-frag][half]: A 2 steps deep
  short8v wr[2][NF];    // [slot][nf]:          W 1 step deep

#pragma unroll
  for (int m = 0; m < 2; ++m)
#pragma unroll
    for (int h = 0; h < 2; ++h) {
      a[0][m][h] = aload(0, m, h);
      a[1][m][h] = aload(1, m, h);
    }
#pragma unroll
  for (int nf = 0; nf < NF; ++nf) wr[0][nf] = wload(0, nf);

#pragma unroll
  for (int kk = 0; kk < NKK; ++kk) {
    if (kk + 2 < NKK) {
#pragma unroll
      for (int m = 0; m < 2; ++m)
#pragma unroll
        for (int h = 0; h < 2; ++h) a[(kk + 2) % 3][m][h] = aload(kk + 2, m, h);
    }
    if (kk + 1 < NKK) {
#pragma unroll
      for (int nf = 0; nf < NF; ++nf) wr[(kk + 1) & 1][nf] = wload(kk + 1, nf);
    }
    // convert current A slot to bf16 fragments
    short8v ah[2];
#pragma unroll
    for (int m = 0; m < 2; ++m) {
#pragma unroll
      for (int j = 0; j < 8; ++j)
        ah[m][j] = bfr((&a[kk % 3][m][j >> 2].x)[j & 3]);
    }
#pragma unroll
    for (int nf = 0; nf < NF; ++nf) {
#pragma unroll
      for (int m = 0; m < 2; ++m)
        acc[m][nf] = __builtin_amdgcn_mfma_f32_16x16x32_bf16(
            ah[m], wr[kk & 1][nf], acc[m][nf], 0, 0, 0);
    }
  }

  // epilogue: C/D layout col=lane&15, row=(lane>>4)*4+reg
#pragma unroll
  for (int m = 0; m < 2; ++m)
#pragma unroll
    for (int nf = 0; nf < NF; ++nf) {
      const size_t r_base = R0 + m * 16 + hi4 * 4;
      const int col = C0 + nf * 16 + lo16;
#pragma unroll
      for (int rr = 0; rr < 4; ++rr)
        out[(r_base + rr) * N_TOT + col] = acc[m][nf][rr];
    }
}

// ---------------- MFMA chunk scan: 16 tasks/block, 32 steps, fp16-2split F ----------------
__global__ __launch_bounds__(1024, 4) void k_mscan(const _Float16* __restrict__ Fhi,
                                                   const _Float16* __restrict__ Flo,
                                                   float* __restrict__ U,
                                                   float* __restrict__ Lst) {
  __shared__ _Float16 sh[16 * 264];
  __shared__ _Float16 sl[16 * 264];

  const int tid = threadIdx.x;
  const int wv = tid >> 6;
  const int l = tid & 63;
  const int lo16 = l & 15, hi4 = l >> 4;
  const int dcol = wv * 16 + lo16;

  const int c = blockIdx.x >> 2;
  const int b0 = (blockIdx.x & 3) * 16;

  half8v fh[8], fl[8];
#pragma unroll
  for (int kk = 0; kk < 8; ++kk) {
    const size_t fo = (size_t)dcol * 256 + kk * 32 + hi4 * 8;
    fh[kk] = *reinterpret_cast<const half8v*>(Fhi + fo);
    fl[kk] = *reinterpret_cast<const half8v*>(Flo + fo);
  }

  const size_t ustr = (size_t)TT * 256;
  float* ub = U + ((size_t)b0 * TT + c * CHUNK) * 256 + dcol;

  float u_cur[4], u_nxt[4];
#pragma unroll
  for (int r = 0; r < 4; ++r) u_cur[r] = ub[(size_t)(hi4 * 4 + r) * ustr];

  for (int k = 0; k < CHUNK; ++k) {
    if (k < CHUNK - 1) {
#pragma unroll
      for (int r = 0; r < 4; ++r)
        u_nxt[r] = ub[(size_t)(hi4 * 4 + r) * ustr + (k + 1) * 256];
    }
    float4v acc;
#pragma unroll
    for (int r = 0; r < 4; ++r) acc[r] = u_cur[r];

    if (k) {
#pragma unroll
      for (int kk = 0; kk < 8; ++kk) {
        const int ao = lo16 * 264 + kk * 32 + hi4 * 8;
        half8v ah = *reinterpret_cast<const half8v*>(&sh[ao]);
        half8v al = *reinterpret_cast<const half8v*>(&sl[ao]);
        acc = __builtin_amdgcn_mfma_f32_16x16x32_f16(ah, fh[kk], acc, 0, 0, 0);
        acc = __builtin_amdgcn_mfma_f32_16x16x32_f16(ah, fl[kk], acc, 0, 0, 0);
        acc = __builtin_amdgcn_mfma_f32_16x16x32_f16(al, fh[kk], acc, 0, 0, 0);
      }
    }

    _Float16 xh[4], xl[4];
#pragma unroll
    for (int r = 0; r < 4; ++r) {
      float x = acc[r];
      ub[(size_t)(hi4 * 4 + r) * ustr + k * 256] = x;
      if (k == CHUNK - 1) Lst[((size_t)c * BATCH + b0 + hi4 * 4 + r) * 256 + dcol] = x;
      _Float16 h = (_Float16)x;
      xh[r] = h;
      xl[r] = (_Float16)(x - (float)h);
    }
    __syncthreads();
#pragma unroll
    for (int r = 0; r < 4; ++r) {
      const int m = hi4 * 4 + r;
      sh[m * 264 + dcol] = xh[r];
      sl[m * 264 + dcol] = xl[r];
    }
    __syncthreads();
#pragma unroll
    for (int r = 0; r < 4; ++r) u_cur[r] = u_nxt[r];
  }
}

// ---------------- MFMA chunk carry: e_{c+1} = F^32 e_c + Lst[c] -> Ebf (bf16) ----------------
__global__ __launch_bounds__(1024, 4) void k_mcarry(const _Float16* __restrict__ FLhi,
                                                    const _Float16* __restrict__ FLlo,
                                                    const float* __restrict__ state0,
                                                    const float* __restrict__ Lst,
                                                    unsigned short* __restrict__ Ebf) {
  __shared__ _Float16 sh[16 * 264];
  __shared__ _Float16 sl[16 * 264];

  const int tid = threadIdx.x;
  const int wv = tid >> 6;
  const int l = tid & 63;
  const int lo16 = l & 15, hi4 = l >> 4;
  const int dcol = wv * 16 + lo16;
  const int b0 = blockIdx.x * 16;

  half8v fh[8], fl[8];
#pragma unroll
  for (int kk = 0; kk < 8; ++kk) {
    const size_t fo = (size_t)dcol * 256 + kk * 32 + hi4 * 8;
    fh[kk] = *reinterpret_cast<const half8v*>(FLhi + fo);
    fl[kk] = *reinterpret_cast<const half8v*>(FLlo + fo);
  }

#pragma unroll
  for (int r = 0; r < 4; ++r) {
    const int m = hi4 * 4 + r;
    float x = state0[(size_t)(b0 + m) * 256 + dcol];
    Ebf[(size_t)(b0 + m) * 256 + dcol] = f2bf(x);
    _Float16 h = (_Float16)x;
    sh[m * 264 + dcol] = h;
    sl[m * 264 + dcol] = (_Float16)(x - (float)h);
  }
  __syncthreads();

  for (int cstep = 0; cstep < NCHUNK - 1; ++cstep) {
    float4v acc;
#pragma unroll
    for (int r = 0; r < 4; ++r)
      acc[r] = Lst[((size_t)cstep * BATCH + b0 + hi4 * 4 + r) * 256 + dcol];
#pragma unroll
    for (int kk = 0; kk < 8; ++kk) {
      const int ao = lo16 * 264 + kk * 32 + hi4 * 8;
      half8v ah = *reinterpret_cast<const half8v*>(&sh[ao]);
      half8v al = *reinterpret_cast<const half8v*>(&sl[ao]);
      acc = __builtin_amdgcn_mfma_f32_16x16x32_f16(ah, fh[kk], acc, 0, 0, 0);
      acc = __builtin_amdgcn_mfma_f32_16x16x32_f16(ah, fl[kk], acc, 0, 0, 0);
      acc = __builtin_amdgcn_mfma_f32_16x16x32_f16(al, fh[kk], acc, 0, 0, 0);
    }
    _Float16 xh[4], xl[4];
#pragma unroll
    for (int r = 0; r < 4; ++r) {
      float x = acc[r];
      Ebf[((size_t)(cstep + 1) * BATCH + b0 + hi4 * 4 + r) * 256 + dcol] = f2bf(x);
      _Float16 h = (_Float16)x;
      xh[r] = h;
      xl[r] = (_Float16)(x - (float)h);
    }
    __syncthreads();
#pragma unroll
    for (int r = 0; r < 4; ++r) {
      const int m = hi4 * 4 + r;
      sh[m * 264 + dcol] = xh[r];
      sl[m * 264 + dcol] = xl[r];
    }
    __syncthreads();
  }
}

// ---------------- correction: states[task, j, :] += F^{j+1} @ e[task]  (bf16 MFMA) ----------------
__global__ __launch_bounds__(256) void k_corr(const unsigned short* __restrict__ Ebf,
                                              const unsigned short* __restrict__ stackbf,
                                              float* __restrict__ states) {
  const int tb = blockIdx.x & 127;
  const int jb = blockIdx.x >> 7;
  const int tid = threadIdx.x;
  const int w = tid >> 6;
  const int l = tid & 63;
  const int lo = l & 15, hi = l >> 4;

  const int M0 = tb * 32 + (w & 1) * 16;
  const int nbase = (w >> 1) * 128;
  const unsigned short* Bj = stackbf + (size_t)jb * 65536;

  float4v acc[8];
#pragma unroll
  for (int nf = 0; nf < 8; ++nf) acc[nf] = (float4v){0.f, 0.f, 0.f, 0.f};

#pragma unroll
  for (int kk = 0; kk < 8; ++kk) {
    const int k0 = kk * 32;
    short8v a = *reinterpret_cast<const short8v*>(Ebf + (size_t)(M0 + lo) * 256 + k0 + hi * 8);
#pragma unroll
    for (int nf = 0; nf < 8; ++nf) {
      const int d0 = nbase + nf * 16;
      short8v bv = *reinterpret_cast<const short8v*>(Bj + (size_t)(d0 + lo) * 256 + k0 + hi * 8);
      acc[nf] = __builtin_amdgcn_mfma_f32_16x16x32_bf16(a, bv, acc[nf], 0, 0, 0);
    }
  }

#pragma unroll
  for (int nf = 0; nf < 8; ++nf) {
    const int d = nbase + nf * 16 + lo;
#pragma unroll
    for (int r = 0; r < 4; ++r) {
      const int task = M0 + hi * 4 + r;
      const int bb = task & 63, cc = task >> 6;
      size_t addr = (((size_t)bb * TT) + cc * CHUNK + jb) * 256 + d;
      states[addr] = states[addr] + acc[nf][r];
    }
  }
}

extern "C" void kernel_launch(void* const* d_in, const int* in_sizes, int n_in,
                              void* d_out, int out_size, void* d_ws, size_t ws_size,
                              hipStream_t stream) {
  const float* state  = (const float*)d_in[0];
  const float* inputs = (const float*)d_in[1];
  const float* eps_W  = (const float*)d_in[2];
  const float* eps_V  = (const float*)d_in[3];
  const float* F      = (const float*)d_in[4];
  const float* B_mat  = (const float*)d_in[5];
  const float* H      = (const float*)d_in[6];
  const float* SW     = (const float*)d_in[7];
  const float* SV     = (const float*)d_in[8];

  float* out = (float*)d_out;
  float* states_out = out;                                 // [64][2048][256]
  float* obs_out = out + (size_t)BATCH * TT * S_DIM;       // [64][2048][64]

  // ws (~720 KB): bf16 weights (single) + fp16 F splits
  unsigned short* ws16 = (unsigned short*)d_ws;
  unsigned short* whi1 = ws16;                 // [256][320]
  unsigned short* whi2 = whi1 + 81920;         // [64][320]
  _Float16* Fhi  = (_Float16*)(whi2 + 20480);  // [256][256]
  _Float16* Flo  = Fhi + 65536;
  _Float16* FLhi = Flo + 65536;                // (F^32) [256][256]
  _Float16* FLlo = FLhi + 65536;

  // big scratch in the dead obs region (18 MB of 33.5 MB)
  float* Lst              = obs_out;                                   // [64][64][256] f32
  float* stack_F          = Lst + (size_t)NCHUNK * BATCH * 256;        // [32][256][256] f32
  unsigned short* stackbf = (unsigned short*)(stack_F + (size_t)32 * 65536);
  unsigned short* Ebf     = stackbf + (size_t)32 * 65536;              // [64][64][256] bf16

  // power stack F^1..F^32 by doubling
  hipMemcpyAsync(stack_F, F, 65536 * sizeof(float), hipMemcpyDeviceToDevice, stream);
  k_powstage<<<1 * 256, 256, 0, stream>>>(stack_F, 1);
  k_powstage<<<2 * 256, 256, 0, stream>>>(stack_F, 2);
  k_powstage<<<4 * 256, 256, 0, stream>>>(stack_F, 4);
  k_powstage<<<8 * 256, 256, 0, stream>>>(stack_F, 8);
  k_powstage<<<16 * 256, 256, 0, stream>>>(stack_F, 16);
  k_bfcvt<<<32 * 65536 / 4 / 256, 256, 0, stream>>>(stack_F, stackbf);

  // fp16 splits for the scan/carry matrices
  k_fsplit16<<<256, 256, 0, stream>>>(F, Fhi, Flo);
  k_fsplit16<<<256, 256, 0, stream>>>(stack_F + (size_t)31 * 65536, FLhi, FLlo);

  // bf16 weights (K-major concat rows, single precision — GEMM error ≪ threshold)
  k_wcvt<<<320, 256, 0, stream>>>(B_mat, SW, 64, 256, whi1, 256 * 320);
  k_wcvt<<<80, 256, 0, stream>>>(H, SV, 256, 64, whi2, 64 * 320);

  // U = inputs@B^T + eps_W@SW^T  (streaming bf16 MFMA, deep prefetch)
  k_rgemm<256, 64, 256, 1, 4><<<BATCH * TT / 32, 256, 0, stream>>>(
      inputs, eps_W, whi1, states_out);

  // pass 1: MFMA local scans (zero init), y in place + Lst
  k_mscan<<<NTASK / 16, 1024, 0, stream>>>(Fhi, Flo, states_out, Lst);

  // carry across chunks -> Ebf
  k_mcarry<<<BATCH / 16, 1024, 0, stream>>>(FLhi, FLlo, state, Lst, Ebf);

  // correction: states = y + F^{j+1} e
  k_corr<<<32 * 128, 256, 0, stream>>>(Ebf, stackbf, states_out);

  // observations = states@H^T + eps_V@SV^T (streaming bf16 MFMA)
  k_rgemm<64, 256, 64, 4, 1><<<BATCH * TT / 128, 256, 0, stream>>>(
      states_out, eps_V, whi2, obs_out);
}

// Round 9
// 560.266 us; speedup vs baseline: 1.2857x; 1.1288x over previous
//
#include <hip/hip_runtime.h>
#include <hip/hip_bf16.h>

#define S_DIM 256
#define I_DIM 64
#define O_DIM 64
#define BATCH 64
#define TT 2048
#define CHUNK 32
#define NCHUNK (TT / CHUNK)     // 64
#define NTASK (BATCH * TT / CHUNK)  // 4096

typedef __attribute__((ext_vector_type(8))) short short8v;      // 8 bf16
typedef _Float16 half8v __attribute__((ext_vector_type(8)));    // 8 fp16
typedef __attribute__((ext_vector_type(4))) float float4v;      // MFMA acc

__device__ inline unsigned short f2bf(float f) {
  unsigned x = __float_as_uint(f);
  unsigned r = (x + 0x7FFFu + ((x >> 16) & 1u)) >> 16;  // RNE
  return (unsigned short)r;
}
__device__ inline short bfr(float x) {
  __hip_bfloat16 h = __float2bfloat16(x);
  return __builtin_bit_cast(short, h);
}

// global -> LDS direct DMA, 16B per lane (dst = wave-uniform base + lane*16)
__device__ inline void gload16(const float* g, float* lds) {
  __builtin_amdgcn_global_load_lds(
      (const __attribute__((address_space(1))) unsigned int*)g,
      (__attribute__((address_space(3))) unsigned int*)lds, 16, 0, 0);
}

// ------------- power-stack doubling: stack[m+j] = stack[j] @ stack[m-1] -------------
__global__ void k_powstage(float* __restrict__ stack, int m) {
  const int j = blockIdx.x >> 8;
  const int i = blockIdx.x & 255;
  const int d = threadIdx.x;
  const float* A = stack + (size_t)j * 65536 + i * 256;
  const float* Bm = stack + (size_t)(m - 1) * 65536;
  float acc = 0.f;
#pragma unroll 8
  for (int k = 0; k < 256; ++k) acc += A[k] * Bm[k * 256 + d];
  stack[(size_t)(m + j) * 65536 + i * 256 + d] = acc;
}

// ------------- f32 -> bf16 elementwise -------------
__global__ void k_bfcvt(const float* __restrict__ src, unsigned short* __restrict__ dst) {
  int i = blockIdx.x * 256 + threadIdx.x;
  float4 v = reinterpret_cast<const float4*>(src)[i];
  ushort4 o;
  o.x = f2bf(v.x); o.y = f2bf(v.y); o.z = f2bf(v.z); o.w = f2bf(v.w);
  reinterpret_cast<ushort4*>(dst)[i] = o;
}

// ------------- f32 matrix -> fp16 hi/lo split -------------
__global__ void k_fsplit16(const float* __restrict__ src, _Float16* __restrict__ hi,
                           _Float16* __restrict__ lo) {
  int idx = blockIdx.x * 256 + threadIdx.x;
  float a = src[idx];
  _Float16 h = (_Float16)a;
  hi[idx] = h;
  lo[idx] = (_Float16)(a - (float)h);
}

// ------------- weight convert: Wd[n][k] = concat(s1,s2) rows, single bf16 -------------
__global__ void k_wcvt(const float* __restrict__ s1, const float* __restrict__ s2,
                       int K1, int K2, unsigned short* __restrict__ hi, int total) {
  int idx = blockIdx.x * 256 + threadIdx.x;
  if (idx >= total) return;
  int KT = K1 + K2;
  int n = idx / KT, k = idx - n * KT;
  float a = (k < K1) ? s1[n * K1 + k] : s2[n * K2 + (k - K1)];
  hi[idx] = f2bf(a);
}

// ---------------- 2-phase LDS-pipelined bf16 MFMA GEMM: out = [A1|A2] @ W^T ----------------
// A-tile staged f32 via global_load_lds (width 16), double-buffered. LDS layout is
// granule-transposed ([g][row] x 16B): linear DMA dest + permuted global source
// (HK m173 pattern) -> read side is 16 consecutive 16B slots per 16-lane group =
// zero bank conflicts, no XOR. W streamed from L2 with 1-kk register rotation.
template <int N_TOT, int K1, int K2, int M_TILE, int WIM, int WIN>
__global__ __launch_bounds__(256, 3) void k_tgemm(
    const float* __restrict__ A1, const float* __restrict__ A2,
    const unsigned short* __restrict__ W, float* __restrict__ out) {
  constexpr int KT = K1 + K2;   // 320
  constexpr int NKT = KT / 64;  // 5 K-tiles
  constexpr int MF = M_TILE / WIM / 16;
  constexpr int NF = N_TOT / WIN / 16;
  constexpr int LOGM = (M_TILE == 64) ? 6 : 7;
  constexpr int CPW = M_TILE / 16;  // gload calls per wave per K-tile

  __shared__ float als[2][M_TILE * 64];

  const int tid = threadIdx.x;
  const int wv = tid >> 6, lane = tid & 63;
  const int lo16 = lane & 15, hi4 = lane >> 4;
  const int wm = wv % WIM, wn = wv / WIM;
  const size_t R0 = (size_t)blockIdx.x * M_TILE;
  const int C0 = wn * (N_TOT / WIN);

  // stage K-tile kt into buffer buf: granule-slot s = i*64+lane, row = s % M_TILE,
  // g = s / M_TILE; source = A[R0+row][kt*64 + g*4 .. +4)
  auto stage = [&](int buf, int kt) {
#pragma unroll
    for (int c = 0; c < CPW; ++c) {
      const int i = wv * CPW + c;
      const int s = i * 64 + lane;
      const int row = s & (M_TILE - 1);
      const int g = s >> LOGM;
      const int k0 = kt * 64;
      const float* src = (k0 < K1) ? A1 + (R0 + row) * K1 + k0 + g * 4
                                   : A2 + (R0 + row) * K2 + (k0 - K1) + g * 4;
      gload16(src, &als[buf][i * 256]);
    }
  };
  auto aread = [&](int buf, int kkl, int m, int h) -> float4 {
    const int row = wm * (M_TILE / WIM) + m * 16 + lo16;
    const int g = kkl * 8 + hi4 * 2 + h;
    return *reinterpret_cast<const float4*>(&als[buf][(g * M_TILE + row) * 4]);
  };
  auto wload = [&](int kk, int nf) -> short8v {
    return *reinterpret_cast<const short8v*>(
        W + (size_t)(C0 + nf * 16 + lo16) * KT + kk * 32 + hi4 * 8);
  };

  float4v acc[MF][NF];
#pragma unroll
  for (int m = 0; m < MF; ++m)
#pragma unroll
    for (int n = 0; n < NF; ++n) acc[m][n] = (float4v){0.f, 0.f, 0.f, 0.f};

  short8v wr[2][NF];
  stage(0, 0);
#pragma unroll
  for (int nf = 0; nf < NF; ++nf) wr[0][nf] = wload(0, nf);
  __syncthreads();

#pragma unroll
  for (int kt = 0; kt < NKT; ++kt) {
    if (kt + 1 < NKT) stage((kt + 1) & 1, kt + 1);  // DMA in flight across compute
#pragma unroll
    for (int kkl = 0; kkl < 2; ++kkl) {
      const int kk = kt * 2 + kkl;
      if (kk + 1 < 2 * NKT) {
#pragma unroll
        for (int nf = 0; nf < NF; ++nf) wr[(kk + 1) & 1][nf] = wload(kk + 1, nf);
      }
      short8v ah[MF];
#pragma unroll
      for (int m = 0; m < MF; ++m) {
        float4 f0 = aread(kt & 1, kkl, m, 0);
        float4 f1 = aread(kt & 1, kkl, m, 1);
#pragma unroll
        for (int j = 0; j < 4; ++j) {
          ah[m][j] = bfr((&f0.x)[j]);
          ah[m][j + 4] = bfr((&f1.x)[j]);
        }
      }
#pragma unroll
      for (int nf = 0; nf < NF; ++nf)
#pragma unroll
        for (int m = 0; m < MF; ++m)
          acc[m][nf] = __builtin_amdgcn_mfma_f32_16x16x32_bf16(
              ah[m], wr[kk & 1][nf], acc[m][nf], 0, 0, 0);
    }
    __syncthreads();  // drains next-tile DMA (vmcnt0) + frees read buffer
  }

  // epilogue: C/D layout col=lane&15, row=(lane>>4)*4+reg
#pragma unroll
  for (int m = 0; m < MF; ++m)
#pragma unroll
    for (int nf = 0; nf < NF; ++nf) {
      const size_t r_base = R0 + wm * (M_TILE / WIM) + m * 16 + hi4 * 4;
      const int col = C0 + nf * 16 + lo16;
#pragma unroll
      for (int rr = 0; rr < 4; ++rr)
        out[(r_base + rr) * N_TOT + col] = acc[m][nf][rr];
    }
}

// ---------------- MFMA chunk scan: 16 tasks/block, 32 steps, fp16-2split F ----------------
__global__ __launch_bounds__(1024, 4) void k_mscan(const _Float16* __restrict__ Fhi,
                                                   const _Float16* __restrict__ Flo,
                                                   float* __restrict__ U,
                                                   float* __restrict__ Lst) {
  __shared__ _Float16 sh[16 * 264];
  __shared__ _Float16 sl[16 * 264];

  const int tid = threadIdx.x;
  const int wv = tid >> 6;
  const int l = tid & 63;
  const int lo16 = l & 15, hi4 = l >> 4;
  const int dcol = wv * 16 + lo16;

  const int c = blockIdx.x >> 2;
  const int b0 = (blockIdx.x & 3) * 16;

  half8v fh[8], fl[8];
#pragma unroll
  for (int kk = 0; kk < 8; ++kk) {
    const size_t fo = (size_t)dcol * 256 + kk * 32 + hi4 * 8;
    fh[kk] = *reinterpret_cast<const half8v*>(Fhi + fo);
    fl[kk] = *reinterpret_cast<const half8v*>(Flo + fo);
  }

  const size_t ustr = (size_t)TT * 256;
  float* ub = U + ((size_t)b0 * TT + c * CHUNK) * 256 + dcol;

  float u_cur[4], u_nxt[4];
#pragma unroll
  for (int r = 0; r < 4; ++r) u_cur[r] = ub[(size_t)(hi4 * 4 + r) * ustr];

  for (int k = 0; k < CHUNK; ++k) {
    if (k < CHUNK - 1) {
#pragma unroll
      for (int r = 0; r < 4; ++r)
        u_nxt[r] = ub[(size_t)(hi4 * 4 + r) * ustr + (k + 1) * 256];
    }
    float4v acc;
#pragma unroll
    for (int r = 0; r < 4; ++r) acc[r] = u_cur[r];

    if (k) {
#pragma unroll
      for (int kk = 0; kk < 8; ++kk) {
        const int ao = lo16 * 264 + kk * 32 + hi4 * 8;
        half8v ah = *reinterpret_cast<const half8v*>(&sh[ao]);
        half8v al = *reinterpret_cast<const half8v*>(&sl[ao]);
        acc = __builtin_amdgcn_mfma_f32_16x16x32_f16(ah, fh[kk], acc, 0, 0, 0);
        acc = __builtin_amdgcn_mfma_f32_16x16x32_f16(ah, fl[kk], acc, 0, 0, 0);
        acc = __builtin_amdgcn_mfma_f32_16x16x32_f16(al, fh[kk], acc, 0, 0, 0);
      }
    }

    _Float16 xh[4], xl[4];
#pragma unroll
    for (int r = 0; r < 4; ++r) {
      float x = acc[r];
      ub[(size_t)(hi4 * 4 + r) * ustr + k * 256] = x;
      if (k == CHUNK - 1) Lst[((size_t)c * BATCH + b0 + hi4 * 4 + r) * 256 + dcol] = x;
      _Float16 h = (_Float16)x;
      xh[r] = h;
      xl[r] = (_Float16)(x - (float)h);
    }
    __syncthreads();
#pragma unroll
    for (int r = 0; r < 4; ++r) {
      const int m = hi4 * 4 + r;
      sh[m * 264 + dcol] = xh[r];
      sl[m * 264 + dcol] = xl[r];
    }
    __syncthreads();
#pragma unroll
    for (int r = 0; r < 4; ++r) u_cur[r] = u_nxt[r];
  }
}

// ---------------- MFMA chunk carry: e_{c+1} = F^32 e_c + Lst[c] -> Ebf (bf16) ----------------
__global__ __launch_bounds__(1024, 4) void k_mcarry(const _Float16* __restrict__ FLhi,
                                                    const _Float16* __restrict__ FLlo,
                                                    const float* __restrict__ state0,
                                                    const float* __restrict__ Lst,
                                                    unsigned short* __restrict__ Ebf) {
  __shared__ _Float16 sh[16 * 264];
  __shared__ _Float16 sl[16 * 264];

  const int tid = threadIdx.x;
  const int wv = tid >> 6;
  const int l = tid & 63;
  const int lo16 = l & 15, hi4 = l >> 4;
  const int dcol = wv * 16 + lo16;
  const int b0 = blockIdx.x * 16;

  half8v fh[8], fl[8];
#pragma unroll
  for (int kk = 0; kk < 8; ++kk) {
    const size_t fo = (size_t)dcol * 256 + kk * 32 + hi4 * 8;
    fh[kk] = *reinterpret_cast<const half8v*>(FLhi + fo);
    fl[kk] = *reinterpret_cast<const half8v*>(FLlo + fo);
  }

#pragma unroll
  for (int r = 0; r < 4; ++r) {
    const int m = hi4 * 4 + r;
    float x = state0[(size_t)(b0 + m) * 256 + dcol];
    Ebf[(size_t)(b0 + m) * 256 + dcol] = f2bf(x);
    _Float16 h = (_Float16)x;
    sh[m * 264 + dcol] = h;
    sl[m * 264 + dcol] = (_Float16)(x - (float)h);
  }
  __syncthreads();

  for (int cstep = 0; cstep < NCHUNK - 1; ++cstep) {
    float4v acc;
#pragma unroll
    for (int r = 0; r < 4; ++r)
      acc[r] = Lst[((size_t)cstep * BATCH + b0 + hi4 * 4 + r) * 256 + dcol];
#pragma unroll
    for (int kk = 0; kk < 8; ++kk) {
      const int ao = lo16 * 264 + kk * 32 + hi4 * 8;
      half8v ah = *reinterpret_cast<const half8v*>(&sh[ao]);
      half8v al = *reinterpret_cast<const half8v*>(&sl[ao]);
      acc = __builtin_amdgcn_mfma_f32_16x16x32_f16(ah, fh[kk], acc, 0, 0, 0);
      acc = __builtin_amdgcn_mfma_f32_16x16x32_f16(ah, fl[kk], acc, 0, 0, 0);
      acc = __builtin_amdgcn_mfma_f32_16x16x32_f16(al, fh[kk], acc, 0, 0, 0);
    }
    _Float16 xh[4], xl[4];
#pragma unroll
    for (int r = 0; r < 4; ++r) {
      float x = acc[r];
      Ebf[((size_t)(cstep + 1) * BATCH + b0 + hi4 * 4 + r) * 256 + dcol] = f2bf(x);
      _Float16 h = (_Float16)x;
      xh[r] = h;
      xl[r] = (_Float16)(x - (float)h);
    }
    __syncthreads();
#pragma unroll
    for (int r = 0; r < 4; ++r) {
      const int m = hi4 * 4 + r;
      sh[m * 264 + dcol] = xh[r];
      sl[m * 264 + dcol] = xl[r];
    }
    __syncthreads();
  }
}

// ---------------- correction: states[task, j, :] += F^{j+1} @ e[task]  (bf16 MFMA) ----------------
__global__ __launch_bounds__(256) void k_corr(const unsigned short* __restrict__ Ebf,
                                              const unsigned short* __restrict__ stackbf,
                                              float* __restrict__ states) {
  const int tb = blockIdx.x & 127;
  const int jb = blockIdx.x >> 7;
  const int tid = threadIdx.x;
  const int w = tid >> 6;
  const int l = tid & 63;
  const int lo = l & 15, hi = l >> 4;

  const int M0 = tb * 32 + (w & 1) * 16;
  const int nbase = (w >> 1) * 128;
  const unsigned short* Bj = stackbf + (size_t)jb * 65536;

  float4v acc[8];
#pragma unroll
  for (int nf = 0; nf < 8; ++nf) acc[nf] = (float4v){0.f, 0.f, 0.f, 0.f};

#pragma unroll
  for (int kk = 0; kk < 8; ++kk) {
    const int k0 = kk * 32;
    short8v a = *reinterpret_cast<const short8v*>(Ebf + (size_t)(M0 + lo) * 256 + k0 + hi * 8);
#pragma unroll
    for (int nf = 0; nf < 8; ++nf) {
      const int d0 = nbase + nf * 16;
      short8v bv = *reinterpret_cast<const short8v*>(Bj + (size_t)(d0 + lo) * 256 + k0 + hi * 8);
      acc[nf] = __builtin_amdgcn_mfma_f32_16x16x32_bf16(a, bv, acc[nf], 0, 0, 0);
    }
  }

#pragma unroll
  for (int nf = 0; nf < 8; ++nf) {
    const int d = nbase + nf * 16 + lo;
#pragma unroll
    for (int r = 0; r < 4; ++r) {
      const int task = M0 + hi * 4 + r;
      const int bb = task & 63, cc = task >> 6;
      size_t addr = (((size_t)bb * TT) + cc * CHUNK + jb) * 256 + d;
      states[addr] = states[addr] + acc[nf][r];
    }
  }
}

extern "C" void kernel_launch(void* const* d_in, const int* in_sizes, int n_in,
                              void* d_out, int out_size, void* d_ws, size_t ws_size,
                              hipStream_t stream) {
  const float* state  = (const float*)d_in[0];
  const float* inputs = (const float*)d_in[1];
  const float* eps_W  = (const float*)d_in[2];
  const float* eps_V  = (const float*)d_in[3];
  const float* F      = (const float*)d_in[4];
  const float* B_mat  = (const float*)d_in[5];
  const float* H      = (const float*)d_in[6];
  const float* SW     = (const float*)d_in[7];
  const float* SV     = (const float*)d_in[8];

  float* out = (float*)d_out;
  float* states_out = out;                                 // [64][2048][256]
  float* obs_out = out + (size_t)BATCH * TT * S_DIM;       // [64][2048][64]

  // ws (~720 KB): bf16 weights + fp16 F splits
  unsigned short* ws16 = (unsigned short*)d_ws;
  unsigned short* whi1 = ws16;                 // [256][320]
  unsigned short* whi2 = whi1 + 81920;         // [64][320]
  _Float16* Fhi  = (_Float16*)(whi2 + 20480);  // [256][256]
  _Float16* Flo  = Fhi + 65536;
  _Float16* FLhi = Flo + 65536;                // (F^32) [256][256]
  _Float16* FLlo = FLhi + 65536;

  // big scratch in the dead obs region (18 MB of 33.5 MB)
  float* Lst              = obs_out;                                   // [64][64][256] f32
  float* stack_F          = Lst + (size_t)NCHUNK * BATCH * 256;        // [32][256][256] f32
  unsigned short* stackbf = (unsigned short*)(stack_F + (size_t)32 * 65536);
  unsigned short* Ebf     = stackbf + (size_t)32 * 65536;              // [64][64][256] bf16

  // power stack F^1..F^32 by doubling
  hipMemcpyAsync(stack_F, F, 65536 * sizeof(float), hipMemcpyDeviceToDevice, stream);
  k_powstage<<<1 * 256, 256, 0, stream>>>(stack_F, 1);
  k_powstage<<<2 * 256, 256, 0, stream>>>(stack_F, 2);
  k_powstage<<<4 * 256, 256, 0, stream>>>(stack_F, 4);
  k_powstage<<<8 * 256, 256, 0, stream>>>(stack_F, 8);
  k_powstage<<<16 * 256, 256, 0, stream>>>(stack_F, 16);
  k_bfcvt<<<32 * 65536 / 4 / 256, 256, 0, stream>>>(stack_F, stackbf);

  // fp16 splits for the scan/carry matrices
  k_fsplit16<<<256, 256, 0, stream>>>(F, Fhi, Flo);
  k_fsplit16<<<256, 256, 0, stream>>>(stack_F + (size_t)31 * 65536, FLhi, FLlo);

  // bf16 weights (K-major concat rows)
  k_wcvt<<<320, 256, 0, stream>>>(B_mat, SW, 64, 256, whi1, 256 * 320);
  k_wcvt<<<80, 256, 0, stream>>>(H, SV, 256, 64, whi2, 64 * 320);

  // U = inputs@B^T + eps_W@SW^T  (2-phase LDS pipeline, global_load_lds)
  k_tgemm<256, 64, 256, 64, 1, 4><<<BATCH * TT / 64, 256, 0, stream>>>(
      inputs, eps_W, whi1, states_out);

  // pass 1: MFMA local scans (zero init), y in place + Lst
  k_mscan<<<NTASK / 16, 1024, 0, stream>>>(Fhi, Flo, states_out, Lst);

  // carry across chunks -> Ebf
  k_mcarry<<<BATCH / 16, 1024, 0, stream>>>(FLhi, FLlo, state, Lst, Ebf);

  // correction: states = y + F^{j+1} e
  k_corr<<<32 * 128, 256, 0, stream>>>(Ebf, stackbf, states_out);

  // observations = states@H^T + eps_V@SV^T
  k_tgemm<64, 256, 64, 128, 4, 1><<<BATCH * TT / 128, 256, 0, stream>>>(
      states_out, eps_V, whi2, obs_out);
}

// Round 10
// 556.298 us; speedup vs baseline: 1.2949x; 1.0071x over previous
//
#include <hip/hip_runtime.h>
#include <hip/hip_bf16.h>

#define S_DIM 256
#define I_DIM 64
#define O_DIM 64
#define BATCH 64
#define TT 2048
#define CHUNK 32
#define NCHUNK (TT / CHUNK)     // 64
#define NTASK (BATCH * TT / CHUNK)  // 4096

typedef __attribute__((ext_vector_type(8))) short short8v;      // 8 bf16
typedef _Float16 half8v __attribute__((ext_vector_type(8)));    // 8 fp16
typedef __attribute__((ext_vector_type(4))) float float4v;      // MFMA acc

__device__ inline unsigned short f2bf(float f) {
  unsigned x = __float_as_uint(f);
  unsigned r = (x + 0x7FFFu + ((x >> 16) & 1u)) >> 16;  // RNE
  return (unsigned short)r;
}
__device__ inline short bfr(float x) {
  __hip_bfloat16 h = __float2bfloat16(x);
  return __builtin_bit_cast(short, h);
}

// global -> LDS direct DMA, 16B per lane (dst = wave-uniform base + lane*16)
__device__ inline void gload16(const float* g, float* lds) {
  __builtin_amdgcn_global_load_lds(
      (const __attribute__((address_space(1))) unsigned int*)g,
      (__attribute__((address_space(3))) unsigned int*)lds, 16, 0, 0);
}

// ------------- power-stack doubling: stack[m+j] = stack[j] @ stack[m-1] -------------
__global__ void k_powstage(float* __restrict__ stack, int m) {
  const int j = blockIdx.x >> 8;
  const int i = blockIdx.x & 255;
  const int d = threadIdx.x;
  const float* A = stack + (size_t)j * 65536 + i * 256;
  const float* Bm = stack + (size_t)(m - 1) * 65536;
  float acc = 0.f;
#pragma unroll 8
  for (int k = 0; k < 256; ++k) acc += A[k] * Bm[k * 256 + d];
  stack[(size_t)(m + j) * 65536 + i * 256 + d] = acc;
}

// ------------- f32 -> bf16 elementwise -------------
__global__ void k_bfcvt(const float* __restrict__ src, unsigned short* __restrict__ dst) {
  int i = blockIdx.x * 256 + threadIdx.x;
  float4 v = reinterpret_cast<const float4*>(src)[i];
  ushort4 o;
  o.x = f2bf(v.x); o.y = f2bf(v.y); o.z = f2bf(v.z); o.w = f2bf(v.w);
  reinterpret_cast<ushort4*>(dst)[i] = o;
}

// ------------- f32 matrix -> fp16 hi/lo split -------------
__global__ void k_fsplit16(const float* __restrict__ src, _Float16* __restrict__ hi,
                           _Float16* __restrict__ lo) {
  int idx = blockIdx.x * 256 + threadIdx.x;
  float a = src[idx];
  _Float16 h = (_Float16)a;
  hi[idx] = h;
  lo[idx] = (_Float16)(a - (float)h);
}

// ------------- weight convert: Wd[n][k] = concat(s1,s2) rows, single bf16 -------------
__global__ void k_wcvt(const float* __restrict__ s1, const float* __restrict__ s2,
                       int K1, int K2, unsigned short* __restrict__ hi, int total) {
  int idx = blockIdx.x * 256 + threadIdx.x;
  if (idx >= total) return;
  int KT = K1 + K2;
  int n = idx / KT, k = idx - n * KT;
  float a = (k < K1) ? s1[n * K1 + k] : s2[n * K2 + (k - K1)];
  hi[idx] = f2bf(a);
}

// ---------------- 2-phase LDS-pipelined bf16 MFMA GEMM: out = [A1|A2] @ W^T ----------------
// A-tile staged f32 via global_load_lds (width 16), double-buffered. LDS layout is
// granule-transposed ([g][row] x 16B): linear DMA dest + permuted global source
// (HK m173 pattern) -> read side is 16 consecutive 16B slots per 16-lane group =
// zero bank conflicts, no XOR. W streamed from L2 with 1-kk register rotation.
template <int N_TOT, int K1, int K2, int M_TILE, int WIM, int WIN>
__global__ __launch_bounds__(256, 3) void k_tgemm(
    const float* __restrict__ A1, const float* __restrict__ A2,
    const unsigned short* __restrict__ W, float* __restrict__ out) {
  constexpr int KT = K1 + K2;   // 320
  constexpr int NKT = KT / 64;  // 5 K-tiles
  constexpr int MF = M_TILE / WIM / 16;
  constexpr int NF = N_TOT / WIN / 16;
  constexpr int LOGM = (M_TILE == 64) ? 6 : 7;
  constexpr int CPW = M_TILE / 16;  // gload calls per wave per K-tile

  __shared__ float als[2][M_TILE * 64];

  const int tid = threadIdx.x;
  const int wv = tid >> 6, lane = tid & 63;
  const int lo16 = lane & 15, hi4 = lane >> 4;
  const int wm = wv % WIM, wn = wv / WIM;
  const size_t R0 = (size_t)blockIdx.x * M_TILE;
  const int C0 = wn * (N_TOT / WIN);

  // stage K-tile kt into buffer buf: granule-slot s = i*64+lane, row = s % M_TILE,
  // g = s / M_TILE; source = A[R0+row][kt*64 + g*4 .. +4)
  auto stage = [&](int buf, int kt) {
#pragma unroll
    for (int c = 0; c < CPW; ++c) {
      const int i = wv * CPW + c;
      const int s = i * 64 + lane;
      const int row = s & (M_TILE - 1);
      const int g = s >> LOGM;
      const int k0 = kt * 64;
      const float* src = (k0 < K1) ? A1 + (R0 + row) * K1 + k0 + g * 4
                                   : A2 + (R0 + row) * K2 + (k0 - K1) + g * 4;
      gload16(src, &als[buf][i * 256]);
    }
  };
  auto aread = [&](int buf, int kkl, int m, int h) -> float4 {
    const int row = wm * (M_TILE / WIM) + m * 16 + lo16;
    const int g = kkl * 8 + hi4 * 2 + h;
    return *reinterpret_cast<const float4*>(&als[buf][(g * M_TILE + row) * 4]);
  };
  auto wload = [&](int kk, int nf) -> short8v {
    return *reinterpret_cast<const short8v*>(
        W + (size_t)(C0 + nf * 16 + lo16) * KT + kk * 32 + hi4 * 8);
  };

  float4v acc[MF][NF];
#pragma unroll
  for (int m = 0; m < MF; ++m)
#pragma unroll
    for (int n = 0; n < NF; ++n) acc[m][n] = (float4v){0.f, 0.f, 0.f, 0.f};

  short8v wr[2][NF];
  stage(0, 0);
#pragma unroll
  for (int nf = 0; nf < NF; ++nf) wr[0][nf] = wload(0, nf);
  __syncthreads();

#pragma unroll
  for (int kt = 0; kt < NKT; ++kt) {
    if (kt + 1 < NKT) stage((kt + 1) & 1, kt + 1);  // DMA in flight across compute
#pragma unroll
    for (int kkl = 0; kkl < 2; ++kkl) {
      const int kk = kt * 2 + kkl;
      if (kk + 1 < 2 * NKT) {
#pragma unroll
        for (int nf = 0; nf < NF; ++nf) wr[(kk + 1) & 1][nf] = wload(kk + 1, nf);
      }
      short8v ah[MF];
#pragma unroll
      for (int m = 0; m < MF; ++m) {
        float4 f0 = aread(kt & 1, kkl, m, 0);
        float4 f1 = aread(kt & 1, kkl, m, 1);
#pragma unroll
        for (int j = 0; j < 4; ++j) {
          ah[m][j] = bfr((&f0.x)[j]);
          ah[m][j + 4] = bfr((&f1.x)[j]);
        }
      }
#pragma unroll
      for (int nf = 0; nf < NF; ++nf)
#pragma unroll
        for (int m = 0; m < MF; ++m)
          acc[m][nf] = __builtin_amdgcn_mfma_f32_16x16x32_bf16(
              ah[m], wr[kk & 1][nf], acc[m][nf], 0, 0, 0);
    }
    __syncthreads();  // drains next-tile DMA (vmcnt0) + frees read buffer
  }

  // epilogue: C/D layout col=lane&15, row=(lane>>4)*4+reg
#pragma unroll
  for (int m = 0; m < MF; ++m)
#pragma unroll
    for (int nf = 0; nf < NF; ++nf) {
      const size_t r_base = R0 + wm * (M_TILE / WIM) + m * 16 + hi4 * 4;
      const int col = C0 + nf * 16 + lo16;
#pragma unroll
      for (int rr = 0; rr < 4; ++rr)
        out[(r_base + rr) * N_TOT + col] = acc[m][nf][rr];
    }
}

// ---------------- MFMA chunk scan: 16 tasks/block, 32 steps, fp16-2split F ----------------
__global__ __launch_bounds__(1024, 4) void k_mscan(const _Float16* __restrict__ Fhi,
                                                   const _Float16* __restrict__ Flo,
                                                   float* __restrict__ U,
                                                   float* __restrict__ Lst) {
  __shared__ _Float16 sh[16 * 264];
  __shared__ _Float16 sl[16 * 264];

  const int tid = threadIdx.x;
  const int wv = tid >> 6;
  const int l = tid & 63;
  const int lo16 = l & 15, hi4 = l >> 4;
  const int dcol = wv * 16 + lo16;

  const int c = blockIdx.x >> 2;
  const int b0 = (blockIdx.x & 3) * 16;

  half8v fh[8], fl[8];
#pragma unroll
  for (int kk = 0; kk < 8; ++kk) {
    const size_t fo = (size_t)dcol * 256 + kk * 32 + hi4 * 8;
    fh[kk] = *reinterpret_cast<const half8v*>(Fhi + fo);
    fl[kk] = *reinterpret_cast<const half8v*>(Flo + fo);
  }

  const size_t ustr = (size_t)TT * 256;
  float* ub = U + ((size_t)b0 * TT + c * CHUNK) * 256 + dcol;

  float u_cur[4], u_nxt[4];
#pragma unroll
  for (int r = 0; r < 4; ++r) u_cur[r] = ub[(size_t)(hi4 * 4 + r) * ustr];

  for (int k = 0; k < CHUNK; ++k) {
    if (k < CHUNK - 1) {
#pragma unroll
      for (int r = 0; r < 4; ++r)
        u_nxt[r] = ub[(size_t)(hi4 * 4 + r) * ustr + (k + 1) * 256];
    }
    float4v acc;
#pragma unroll
    for (int r = 0; r < 4; ++r) acc[r] = u_cur[r];

    if (k) {
#pragma unroll
      for (int kk = 0; kk < 8; ++kk) {
        const int ao = lo16 * 264 + kk * 32 + hi4 * 8;
        half8v ah = *reinterpret_cast<const half8v*>(&sh[ao]);
        half8v al = *reinterpret_cast<const half8v*>(&sl[ao]);
        acc = __builtin_amdgcn_mfma_f32_16x16x32_f16(ah, fh[kk], acc, 0, 0, 0);
        acc = __builtin_amdgcn_mfma_f32_16x16x32_f16(ah, fl[kk], acc, 0, 0, 0);
        acc = __builtin_amdgcn_mfma_f32_16x16x32_f16(al, fh[kk], acc, 0, 0, 0);
      }
    }

    _Float16 xh[4], xl[4];
#pragma unroll
    for (int r = 0; r < 4; ++r) {
      float x = acc[r];
      ub[(size_t)(hi4 * 4 + r) * ustr + k * 256] = x;
      if (k == CHUNK - 1) Lst[((size_t)c * BATCH + b0 + hi4 * 4 + r) * 256 + dcol] = x;
      _Float16 h = (_Float16)x;
      xh[r] = h;
      xl[r] = (_Float16)(x - (float)h);
    }
    __syncthreads();
#pragma unroll
    for (int r = 0; r < 4; ++r) {
      const int m = hi4 * 4 + r;
      sh[m * 264 + dcol] = xh[r];
      sl[m * 264 + dcol] = xl[r];
    }
    __syncthreads();
#pragma unroll
    for (int r = 0; r < 4; ++r) u_cur[r] = u_nxt[r];
  }
}

// ---------------- MFMA chunk carry: e_{c+1} = F^32 e_c + Lst[c] -> Ebf (bf16) ----------------
__global__ __launch_bounds__(1024, 4) void k_mcarry(const _Float16* __restrict__ FLhi,
                                                    const _Float16* __restrict__ FLlo,
                                                    const float* __restrict__ state0,
                                                    const float* __restrict__ Lst,
                                                    unsigned short* __restrict__ Ebf) {
  __shared__ _Float16 sh[16 * 264];
  __shared__ _Float16 sl[16 * 264];

  const int tid = threadIdx.x;
  const int wv = tid >> 6;
  const int l = tid & 63;
  const int lo16 = l & 15, hi4 = l >> 4;
  const int dcol = wv * 16 + lo16;
  const int b0 = blockIdx.x * 16;

  half8v fh[8], fl[8];
#pragma unroll
  for (int kk = 0; kk < 8; ++kk) {
    const size_t fo = (size_t)dcol * 256 + kk * 32 + hi4 * 8;
    fh[kk] = *reinterpret_cast<const half8v*>(FLhi + fo);
    fl[kk] = *reinterpret_cast<const half8v*>(FLlo + fo);
  }

#pragma unroll
  for (int r = 0; r < 4; ++r) {
    const int m = hi4 * 4 + r;
    float x = state0[(size_t)(b0 + m) * 256 + dcol];
    Ebf[(size_t)(b0 + m) * 256 + dcol] = f2bf(x);
    _Float16 h = (_Float16)x;
    sh[m * 264 + dcol] = h;
    sl[m * 264 + dcol] = (_Float16)(x - (float)h);
  }
  __syncthreads();

  for (int cstep = 0; cstep < NCHUNK - 1; ++cstep) {
    float4v acc;
#pragma unroll
    for (int r = 0; r < 4; ++r)
      acc[r] = Lst[((size_t)cstep * BATCH + b0 + hi4 * 4 + r) * 256 + dcol];
#pragma unroll
    for (int kk = 0; kk < 8; ++kk) {
      const int ao = lo16 * 264 + kk * 32 + hi4 * 8;
      half8v ah = *reinterpret_cast<const half8v*>(&sh[ao]);
      half8v al = *reinterpret_cast<const half8v*>(&sl[ao]);
      acc = __builtin_amdgcn_mfma_f32_16x16x32_f16(ah, fh[kk], acc, 0, 0, 0);
      acc = __builtin_amdgcn_mfma_f32_16x16x32_f16(ah, fl[kk], acc, 0, 0, 0);
      acc = __builtin_amdgcn_mfma_f32_16x16x32_f16(al, fh[kk], acc, 0, 0, 0);
    }
    _Float16 xh[4], xl[4];
#pragma unroll
    for (int r = 0; r < 4; ++r) {
      float x = acc[r];
      Ebf[((size_t)(cstep + 1) * BATCH + b0 + hi4 * 4 + r) * 256 + dcol] = f2bf(x);
      _Float16 h = (_Float16)x;
      xh[r] = h;
      xl[r] = (_Float16)(x - (float)h);
    }
    __syncthreads();
#pragma unroll
    for (int r = 0; r < 4; ++r) {
      const int m = hi4 * 4 + r;
      sh[m * 264 + dcol] = xh[r];
      sl[m * 264 + dcol] = xl[r];
    }
    __syncthreads();
  }
}

// ---------------- correction: states[task, j, :] += F^{j+1} @ e[task]  (bf16 MFMA) ----------------
__global__ __launch_bounds__(256) void k_corr(const unsigned short* __restrict__ Ebf,
                                              const unsigned short* __restrict__ stackbf,
                                              float* __restrict__ states) {
  const int tb = blockIdx.x & 127;
  const int jb = blockIdx.x >> 7;
  const int tid = threadIdx.x;
  const int w = tid >> 6;
  const int l = tid & 63;
  const int lo = l & 15, hi = l >> 4;

  const int M0 = tb * 32 + (w & 1) * 16;
  const int nbase = (w >> 1) * 128;
  const unsigned short* Bj = stackbf + (size_t)jb * 65536;

  float4v acc[8];
#pragma unroll
  for (int nf = 0; nf < 8; ++nf) acc[nf] = (float4v){0.f, 0.f, 0.f, 0.f};

#pragma unroll
  for (int kk = 0; kk < 8; ++kk) {
    const int k0 = kk * 32;
    short8v a = *reinterpret_cast<const short8v*>(Ebf + (size_t)(M0 + lo) * 256 + k0 + hi * 8);
#pragma unroll
    for (int nf = 0; nf < 8; ++nf) {
      const int d0 = nbase + nf * 16;
      short8v bv = *reinterpret_cast<const short8v*>(Bj + (size_t)(d0 + lo) * 256 + k0 + hi * 8);
      acc[nf] = __builtin_amdgcn_mfma_f32_16x16x32_bf16(a, bv, acc[nf], 0, 0, 0);
    }
  }

#pragma unroll
  for (int nf = 0; nf < 8; ++nf) {
    const int d = nbase + nf * 16 + lo;
#pragma unroll
    for (int r = 0; r < 4; ++r) {
      const int task = M0 + hi * 4 + r;
      const int bb = task & 63, cc = task >> 6;
      size_t addr = (((size_t)bb * TT) + cc * CHUNK + jb) * 256 + d;
      states[addr] = states[addr] + acc[nf][r];
    }
  }
}

extern "C" void kernel_launch(void* const* d_in, const int* in_sizes, int n_in,
                              void* d_out, int out_size, void* d_ws, size_t ws_size,
                              hipStream_t stream) {
  const float* state  = (const float*)d_in[0];
  const float* inputs = (const float*)d_in[1];
  const float* eps_W  = (const float*)d_in[2];
  const float* eps_V  = (const float*)d_in[3];
  const float* F      = (const float*)d_in[4];
  const float* B_mat  = (const float*)d_in[5];
  const float* H      = (const float*)d_in[6];
  const float* SW     = (const float*)d_in[7];
  const float* SV     = (const float*)d_in[8];

  float* out = (float*)d_out;
  float* states_out = out;                                 // [64][2048][256]
  float* obs_out = out + (size_t)BATCH * TT * S_DIM;       // [64][2048][64]

  // ws (~720 KB): bf16 weights + fp16 F splits
  unsigned short* ws16 = (unsigned short*)d_ws;
  unsigned short* whi1 = ws16;                 // [256][320]
  unsigned short* whi2 = whi1 + 81920;         // [64][320]
  _Float16* Fhi  = (_Float16*)(whi2 + 20480);  // [256][256]
  _Float16* Flo  = Fhi + 65536;
  _Float16* FLhi = Flo + 65536;                // (F^32) [256][256]
  _Float16* FLlo = FLhi + 65536;

  // big scratch in the dead obs region (18 MB of 33.5 MB)
  float* Lst              = obs_out;                                   // [64][64][256] f32
  float* stack_F          = Lst + (size_t)NCHUNK * BATCH * 256;        // [32][256][256] f32
  unsigned short* stackbf = (unsigned short*)(stack_F + (size_t)32 * 65536);
  unsigned short* Ebf     = stackbf + (size_t)32 * 65536;              // [64][64][256] bf16

  // power stack F^1..F^32 by doubling
  hipMemcpyAsync(stack_F, F, 65536 * sizeof(float), hipMemcpyDeviceToDevice, stream);
  k_powstage<<<1 * 256, 256, 0, stream>>>(stack_F, 1);
  k_powstage<<<2 * 256, 256, 0, stream>>>(stack_F, 2);
  k_powstage<<<4 * 256, 256, 0, stream>>>(stack_F, 4);
  k_powstage<<<8 * 256, 256, 0, stream>>>(stack_F, 8);
  k_powstage<<<16 * 256, 256, 0, stream>>>(stack_F, 16);
  k_bfcvt<<<32 * 65536 / 4 / 256, 256, 0, stream>>>(stack_F, stackbf);

  // fp16 splits for the scan/carry matrices
  k_fsplit16<<<256, 256, 0, stream>>>(F, Fhi, Flo);
  k_fsplit16<<<256, 256, 0, stream>>>(stack_F + (size_t)31 * 65536, FLhi, FLlo);

  // bf16 weights (K-major concat rows)
  k_wcvt<<<320, 256, 0, stream>>>(B_mat, SW, 64, 256, whi1, 256 * 320);
  k_wcvt<<<80, 256, 0, stream>>>(H, SV, 256, 64, whi2, 64 * 320);

  // U = inputs@B^T + eps_W@SW^T  (2-phase LDS pipeline, global_load_lds)
  k_tgemm<256, 64, 256, 64, 1, 4><<<BATCH * TT / 64, 256, 0, stream>>>(
      inputs, eps_W, whi1, states_out);

  // pass 1: MFMA local scans (zero init), y in place + Lst
  k_mscan<<<NTASK / 16, 1024, 0, stream>>>(Fhi, Flo, states_out, Lst);

  // carry across chunks -> Ebf
  k_mcarry<<<BATCH / 16, 1024, 0, stream>>>(FLhi, FLlo, state, Lst, Ebf);

  // correction: states = y + F^{j+1} e
  k_corr<<<32 * 128, 256, 0, stream>>>(Ebf, stackbf, states_out);

  // observations = states@H^T + eps_V@SV^T
  k_tgemm<64, 256, 64, 128, 4, 1><<<BATCH * TT / 128, 256, 0, stream>>>(
      states_out, eps_V, whi2, obs_out);
}